// Round 5
// baseline (1347.429 us; speedup 1.0000x reference)
//
#include <hip/hip_runtime.h>
#include <math.h>

typedef _Float16 f16;
typedef _Float16 f16x8 __attribute__((ext_vector_type(8)));
typedef float    f32x4 __attribute__((ext_vector_type(4)));

#define MFMA16(A, B, C) __builtin_amdgcn_mfma_f32_16x16x32_f16((A), (B), (C), 0, 0, 0)

// acc is pre-scaled: acc = -z (sigmoid gates) or -2z (tanh gate / cell).
// sigmoid(z) = rcp(1 + e^-z); tanh(z) = 2*rcp(1+e^-2z) - 1.
__device__ __forceinline__ float sig_pre(float a) {
    return __builtin_amdgcn_rcpf(1.0f + __expf(a));
}

// B-fragment of W^T with scale s folded in: lane holds B[k0+j][n] = s*W[n][k0+j].
__device__ __forceinline__ f16x8 ldfrag(const float* __restrict__ W, int n, int k0, float s) {
    const float* p = W + (size_t)n * 64 + k0;
    f16x8 r;
#pragma unroll
    for (int j = 0; j < 8; j++) r[j] = (f16)(s * p[j]);
    return r;
}

// One block per batch element; 256 threads = 4 waves.
// Wave wv owns gate columns n = g*64 + wv*16 + (lane&15), g = i,f,g,o.
// A-fragments broadcast (M=1); h state double-buffered in LDS.
// Encoder is layer-pipelined: tick tau computes L1(tau) and L2(tau-1) -> 1 barrier/tick.
__global__ __launch_bounds__(256, 2)
void seq2seq_kernel(const float* __restrict__ src, const float* __restrict__ trg,
                    const float* __restrict__ e1ih, const float* __restrict__ e1hh,
                    const float* __restrict__ e1b,
                    const float* __restrict__ e2ih, const float* __restrict__ e2hh,
                    const float* __restrict__ e2b,
                    const float* __restrict__ d1ih, const float* __restrict__ d1hh,
                    const float* __restrict__ d1b,
                    const float* __restrict__ d2ih, const float* __restrict__ d2hh,
                    const float* __restrict__ d2b,
                    const float* __restrict__ fcW, const float* __restrict__ fcb,
                    float* __restrict__ out)
{
    const int b    = blockIdx.x;
    const int tid  = threadIdx.x;
    const int wv   = tid >> 6;
    const int lane = tid & 63;
    const int quad = lane >> 4;
    const int l15  = lane & 15;
    const int u    = wv * 16 + l15;          // hidden index this lane owns

    __shared__ __align__(16) f16 h1l[2][64];
    __shared__ __align__(16) f16 h2l[2][64];

    // ---- encoder weights: prescaled register-resident B-fragments ----
    f16x8 E1hh[4][2], E2ih[4][2], E2hh[4][2];
    float xw[4][3], bias1[4], bias2[4];
#pragma unroll
    for (int g = 0; g < 4; g++) {
        const float s = (g == 2) ? -2.0f : -1.0f;
        const int n = g * 64 + u;
#pragma unroll
        for (int c = 0; c < 2; c++) {
            const int k0 = c * 32 + quad * 8;
            E1hh[g][c] = ldfrag(e1hh, n, k0, s);
            E2ih[g][c] = ldfrag(e2ih, n, k0, s);
            E2hh[g][c] = ldfrag(e2hh, n, k0, s);
        }
        xw[g][0] = s * e1ih[n * 3 + 0];
        xw[g][1] = s * e1ih[n * 3 + 1];
        xw[g][2] = s * e1ih[n * 3 + 2];
        bias1[g] = s * e1b[n];
        bias2[g] = s * e2b[n];
    }

    float c1 = 0.f, c2 = 0.f;
    if (tid < 64) {
        h1l[0][tid] = (f16)0.f; h1l[1][tid] = (f16)0.f;
        h2l[0][tid] = (f16)0.f; h2l[1][tid] = (f16)0.f;
    }
    __syncthreads();

    const float* srow = src + (size_t)b * 3072;
    float x0 = srow[0], x1 = srow[1], x2 = srow[2];
    const f32x4 z4 = {0.f, 0.f, 0.f, 0.f};

    // ---------------- encoder: 1025 pipelined ticks, 1 barrier each --------
#pragma unroll 1
    for (int tau = 0; tau <= 1024; tau++) {
        const int w = tau & 1;
        // prefetch x(tau+1) (hidden behind the whole tick)
        const int tn = (tau + 1 < 1024) ? tau + 1 : 1023;
        float nx0 = srow[tn * 3], nx1 = srow[tn * 3 + 1], nx2 = srow[tn * 3 + 2];

        const f16* h1p = h1l[w ^ 1];       // h1(tau-1)
        const f16* h2p = h2l[w ^ 1];       // h2(tau-2)
        f16x8 a0 = *(const f16x8*)(h1p + quad * 8);
        f16x8 a1 = *(const f16x8*)(h1p + 32 + quad * 8);
        f16x8 b0 = *(const f16x8*)(h2p + quad * 8);
        f16x8 b1 = *(const f16x8*)(h2p + 32 + quad * 8);

        if (tau < 1024) {                  // L1: h1(tau) from h1(tau-1), x(tau)
            f32x4 acc[4];
#pragma unroll
            for (int g = 0; g < 4; g++)
                acc[g] = MFMA16(a1, E1hh[g][1], MFMA16(a0, E1hh[g][0], z4));
            float v[4];
#pragma unroll
            for (int g = 0; g < 4; g++)
                v[g] = acc[g][0] +
                       fmaf(xw[g][0], x0, fmaf(xw[g][1], x1, fmaf(xw[g][2], x2, bias1[g])));
            float iv = sig_pre(v[0]), fv = sig_pre(v[1]);
            float gv = 2.0f * sig_pre(v[2]) - 1.0f, ov = sig_pre(v[3]);
            c1 = fv * c1 + iv * gv;
            float th = 2.0f * sig_pre(-2.0f * c1) - 1.0f;
            if (quad == 0) h1l[w][u] = (f16)(ov * th);
        }
        if (tau > 0) {                     // L2: h2(tau-1) from h1(tau-1), h2(tau-2)
            f32x4 acc[4];
#pragma unroll
            for (int g = 0; g < 4; g++)
                acc[g] = MFMA16(b1, E2hh[g][1], MFMA16(b0, E2hh[g][0],
                         MFMA16(a1, E2ih[g][1], MFMA16(a0, E2ih[g][0], z4))));
            float v[4];
#pragma unroll
            for (int g = 0; g < 4; g++) v[g] = acc[g][0] + bias2[g];
            float iv = sig_pre(v[0]), fv = sig_pre(v[1]);
            float gv = 2.0f * sig_pre(v[2]) - 1.0f, ov = sig_pre(v[3]);
            c2 = fv * c2 + iv * gv;
            float th = 2.0f * sig_pre(-2.0f * c2) - 1.0f;
            if (quad == 0) h2l[w][u] = (f16)(ov * th);
        }
        __syncthreads();
        x0 = nx0; x1 = nx1; x2 = nx2;
    }
    // encoder final: h2(1023) in h2l[0], c2 replicated in regs

    // ---------------- decoder weights (reuse dead encoder registers) -------
    f16x8 D1hh[4][2], W2s[4][2];
    float dxw[4][3], db1[4], db2[4];
#pragma unroll
    for (int g = 0; g < 4; g++) {
        const float s = (g == 2) ? -2.0f : -1.0f;
        const int n = g * 64 + u;
#pragma unroll
        for (int c = 0; c < 2; c++) {
            const int k0 = c * 32 + quad * 8;
            D1hh[g][c] = ldfrag(d1hh, n, k0, s);
            const float* pa = d2ih + (size_t)n * 64 + k0;
            const float* pb = d2hh + (size_t)n * 64 + k0;
            f16x8 r;
#pragma unroll
            for (int j = 0; j < 8; j++) r[j] = (f16)(s * (pa[j] + pb[j]));
            W2s[g][c] = r;
        }
        dxw[g][0] = s * d1ih[n * 3 + 0];
        dxw[g][1] = s * d1ih[n * 3 + 1];
        dxw[g][2] = s * d1ih[n * 3 + 2];
        db1[g] = s * d1b[n];
        db2[g] = s * d2b[n];
    }
    float fw0 = 0.f, fw1 = 0.f, fw2 = 0.f;
    float fb0 = fcb[0], fb1 = fcb[1], fb2 = fcb[2];
    if (wv == 0) { fw0 = fcW[lane]; fw1 = fcW[64 + lane]; fw2 = fcW[128 + lane]; }

    float cd = c2;
    const float* trow = trg + (size_t)b * 1536;
    float t0 = trow[0], t1 = trow[1], t2v = trow[2];

    // ---------------- decoder: 511 steps, 2 barriers each ------------------
#pragma unroll 1
    for (int t = 0; t < 511; t++) {
        const int r = t & 1, w = r ^ 1;
        const int tn = (t + 1 < 511) ? t + 1 : 510;
        float n0x = trow[tn * 3], n1x = trow[tn * 3 + 1], n2x = trow[tn * 3 + 2];

        const f16* hp = h2l[r];            // hD(t-1)
        f16x8 a0 = *(const f16x8*)(hp + quad * 8);
        f16x8 a1 = *(const f16x8*)(hp + 32 + quad * 8);

        // dec1
        f32x4 acc[4];
#pragma unroll
        for (int g = 0; g < 4; g++)
            acc[g] = MFMA16(a1, D1hh[g][1], MFMA16(a0, D1hh[g][0], z4));
        float v[4];
#pragma unroll
        for (int g = 0; g < 4; g++)
            v[g] = acc[g][0] +
                   fmaf(dxw[g][0], t0, fmaf(dxw[g][1], t1, fmaf(dxw[g][2], t2v, db1[g])));
        float iv = sig_pre(v[0]), fv = sig_pre(v[1]);
        float gv = 2.0f * sig_pre(v[2]) - 1.0f, ov = sig_pre(v[3]);
        float c1d = fv * cd + iv * gv;
        float th1 = 2.0f * sig_pre(-2.0f * c1d) - 1.0f;
        if (quad == 0) h1l[w][u] = (f16)(ov * th1);
        __syncthreads();   // B1: h1d visible

        // dec2: x = h = h1d -> summed (Wih2+Whh2)
        const f16* np = h1l[w];
        f16x8 n0 = *(const f16x8*)(np + quad * 8);
        f16x8 n1 = *(const f16x8*)(np + 32 + quad * 8);
#pragma unroll
        for (int g = 0; g < 4; g++)
            acc[g] = MFMA16(n1, W2s[g][1], MFMA16(n0, W2s[g][0], z4));
#pragma unroll
        for (int g = 0; g < 4; g++) v[g] = acc[g][0] + db2[g];
        float i2 = sig_pre(v[0]), f2 = sig_pre(v[1]);
        float g2 = 2.0f * sig_pre(v[2]) - 1.0f, o2 = sig_pre(v[3]);
        float c2d = f2 * c1d + i2 * g2;
        float th2 = 2.0f * sig_pre(-2.0f * c2d) - 1.0f;
        cd = c2d;
        if (quad == 0) h2l[w][u] = (f16)(o2 * th2);
        __syncthreads();   // B2: hD(t) visible

        if (wv == 0) {     // FC head
            float hv = (float)h2l[w][lane];
            float p0 = fw0 * hv, p1 = fw1 * hv, p2 = fw2 * hv;
#pragma unroll
            for (int off = 32; off > 0; off >>= 1) {
                p0 += __shfl_down(p0, off);
                p1 += __shfl_down(p1, off);
                p2 += __shfl_down(p2, off);
            }
            if (lane == 0) {
                float* o = out + ((size_t)b * 512 + t + 1) * 3;
                o[0] = p0 + fb0; o[1] = p1 + fb1; o[2] = p2 + fb2;
            }
        }
        t0 = n0x; t1 = n1x; t2v = n2x;
    }
}

extern "C" void kernel_launch(void* const* d_in, const int* in_sizes, int n_in,
                              void* d_out, int out_size, void* d_ws, size_t ws_size,
                              hipStream_t stream)
{
    const float* src   = (const float*)d_in[0];
    const float* trg   = (const float*)d_in[1];
    const float* e1ih  = (const float*)d_in[2];
    const float* e1hh  = (const float*)d_in[3];
    const float* e1b   = (const float*)d_in[4];
    const float* e2ih  = (const float*)d_in[5];
    const float* e2hh  = (const float*)d_in[6];
    const float* e2b   = (const float*)d_in[7];
    const float* dd1ih = (const float*)d_in[8];
    const float* dd1hh = (const float*)d_in[9];
    const float* dd1b  = (const float*)d_in[10];
    const float* dd2ih = (const float*)d_in[11];
    const float* dd2hh = (const float*)d_in[12];
    const float* dd2b  = (const float*)d_in[13];
    const float* fcW   = (const float*)d_in[14];
    const float* fcb   = (const float*)d_in[15];
    float* out = (float*)d_out;

    // outputs[:, 0, :] stays 0; decoder fills t >= 1
    hipMemsetAsync(d_out, 0, (size_t)out_size * sizeof(float), stream);

    seq2seq_kernel<<<512, 256, 0, stream>>>(src, trg,
                                            e1ih, e1hh, e1b, e2ih, e2hh, e2b,
                                            dd1ih, dd1hh, dd1b, dd2ih, dd2hh, dd2b,
                                            fcW, fcb, out);
}

// Round 6
// 1192.899 us; speedup vs baseline: 1.1295x; 1.1295x over previous
//
#include <hip/hip_runtime.h>
#include <math.h>

typedef _Float16 f16;
typedef _Float16 f16x8 __attribute__((ext_vector_type(8)));
typedef float    f32x4 __attribute__((ext_vector_type(4)));

#define MFMA16(A, B, C) __builtin_amdgcn_mfma_f32_16x16x32_f16((A), (B), (C), 0, 0, 0)

// acc is pre-scaled: acc = -z (sigmoid gates) or -2z (tanh gate / cell).
__device__ __forceinline__ float sig_pre(float a) {
    return __builtin_amdgcn_rcpf(1.0f + __expf(a));
}

// B-fragment of W^T with scale s folded in: lane holds B[k0+j][n] = s*W[n][k0+j].
__device__ __forceinline__ f16x8 ldfrag(const float* __restrict__ W, int n, int k0, float s) {
    const float* p = W + (size_t)n * 64 + k0;
    f16x8 r;
#pragma unroll
    for (int j = 0; j < 8; j++) r[j] = (f16)(s * p[j]);
    return r;
}

// One block per BATCH PAIR (M=2 real MFMA rows); 256 blocks, 256 threads = 4 waves.
// Wave wv owns gate columns n = g*64 + wv*16 + (lane&15).
// A row m = batch (m&1)  ->  C row r = batch (r&1): reg0 = batch0, reg1 = batch1.
// Quads (0,2) process batch0, quads (1,3) batch1 (2x redundant, uniform code).
__global__ __launch_bounds__(256, 2)
void seq2seq_kernel(const float* __restrict__ src, const float* __restrict__ trg,
                    const float* __restrict__ e1ih, const float* __restrict__ e1hh,
                    const float* __restrict__ e1b,
                    const float* __restrict__ e2ih, const float* __restrict__ e2hh,
                    const float* __restrict__ e2b,
                    const float* __restrict__ d1ih, const float* __restrict__ d1hh,
                    const float* __restrict__ d1b,
                    const float* __restrict__ d2ih, const float* __restrict__ d2hh,
                    const float* __restrict__ d2b,
                    const float* __restrict__ fcW, const float* __restrict__ fcb,
                    float* __restrict__ out)
{
    const int bp   = blockIdx.x;             // batch pair: batches 2bp, 2bp+1
    const int tid  = threadIdx.x;
    const int wv   = tid >> 6;
    const int lane = tid & 63;
    const int quad = lane >> 4;
    const int c15  = lane & 15;
    const int u16  = wv * 16 + c15;          // hidden index this lane owns
    const int qb   = quad & 1;               // batch this lane processes
    const int ab   = c15 & 1;                // batch this lane's A-row feeds

    __shared__ __align__(16) f16 h1l[2][2][64];   // [buf][bat][u]
    __shared__ __align__(16) f16 h2l[2][2][64];

    // ---- encoder weights: prescaled register-resident B-fragments ----
    f16x8 E1hh[4][2], E2ih[4][2], E2hh[4][2];
    float xw[4][3], bias1[4], bias2[4];
#pragma unroll
    for (int g = 0; g < 4; g++) {
        const float s = (g == 2) ? -2.0f : -1.0f;
        const int n = g * 64 + u16;
#pragma unroll
        for (int c = 0; c < 2; c++) {
            const int k0 = c * 32 + quad * 8;
            E1hh[g][c] = ldfrag(e1hh, n, k0, s);
            E2ih[g][c] = ldfrag(e2ih, n, k0, s);
            E2hh[g][c] = ldfrag(e2hh, n, k0, s);
        }
        xw[g][0] = s * e1ih[n * 3 + 0];
        xw[g][1] = s * e1ih[n * 3 + 1];
        xw[g][2] = s * e1ih[n * 3 + 2];
        bias1[g] = s * e1b[n];
        bias2[g] = s * e2b[n];
    }

    float c1 = 0.f, c2 = 0.f;                // state for (u16, qb)
    {
        f16* p1 = &h1l[0][0][0];
        f16* p2 = &h2l[0][0][0];
        p1[tid] = (f16)0.f;                  // 256 entries = 2*2*64
        p2[tid] = (f16)0.f;
    }
    __syncthreads();

    const float* srow0 = src + (size_t)(2 * bp) * 3072;
    const float* srow1 = src + (size_t)(2 * bp + 1) * 3072;
    float x00 = srow0[0], x01 = srow0[1], x02 = srow0[2];
    float x10 = srow1[0], x11 = srow1[1], x12 = srow1[2];
    const f32x4 z4 = {0.f, 0.f, 0.f, 0.f};

    // ---------------- encoder: 1025 pipelined ticks, 1 barrier each --------
#pragma unroll 1
    for (int tau = 0; tau <= 1024; tau++) {
        const int w = tau & 1;
        const int tn = (tau + 1 < 1024) ? tau + 1 : 1023;
        float nx00 = srow0[tn * 3], nx01 = srow0[tn * 3 + 1], nx02 = srow0[tn * 3 + 2];
        float nx10 = srow1[tn * 3], nx11 = srow1[tn * 3 + 1], nx12 = srow1[tn * 3 + 2];

        const f16* h1p = h1l[w ^ 1][ab];     // h1(tau-1), batch ab rows
        const f16* h2p = h2l[w ^ 1][ab];     // h2(tau-2)
        f16x8 a0 = *(const f16x8*)(h1p + quad * 8);
        f16x8 a1 = *(const f16x8*)(h1p + 32 + quad * 8);
        f16x8 b0 = *(const f16x8*)(h2p + quad * 8);
        f16x8 b1 = *(const f16x8*)(h2p + 32 + quad * 8);

        const float xs0 = qb ? x10 : x00;
        const float xs1 = qb ? x11 : x01;
        const float xs2 = qb ? x12 : x02;

        if (tau < 1024) {                    // L1: h1(tau)
            f32x4 acc[4];
#pragma unroll
            for (int g = 0; g < 4; g++)
                acc[g] = MFMA16(a1, E1hh[g][1], MFMA16(a0, E1hh[g][0], z4));
            float v[4];
#pragma unroll
            for (int g = 0; g < 4; g++) {
                float av = qb ? acc[g][1] : acc[g][0];
                v[g] = av + fmaf(xw[g][0], xs0,
                            fmaf(xw[g][1], xs1, fmaf(xw[g][2], xs2, bias1[g])));
            }
            float iv = sig_pre(v[0]), fv = sig_pre(v[1]);
            float gv = 2.0f * sig_pre(v[2]) - 1.0f, ov = sig_pre(v[3]);
            c1 = fv * c1 + iv * gv;
            float th = 2.0f * sig_pre(-2.0f * c1) - 1.0f;
            if (quad < 2) h1l[w][quad][u16] = (f16)(ov * th);
        }
        if (tau > 0) {                       // L2: h2(tau-1)
            f32x4 acc[4];
#pragma unroll
            for (int g = 0; g < 4; g++)
                acc[g] = MFMA16(b1, E2hh[g][1], MFMA16(b0, E2hh[g][0],
                         MFMA16(a1, E2ih[g][1], MFMA16(a0, E2ih[g][0], z4))));
            float v[4];
#pragma unroll
            for (int g = 0; g < 4; g++) {
                float av = qb ? acc[g][1] : acc[g][0];
                v[g] = av + bias2[g];
            }
            float iv = sig_pre(v[0]), fv = sig_pre(v[1]);
            float gv = 2.0f * sig_pre(v[2]) - 1.0f, ov = sig_pre(v[3]);
            c2 = fv * c2 + iv * gv;
            float th = 2.0f * sig_pre(-2.0f * c2) - 1.0f;
            if (quad < 2) h2l[w][quad][u16] = (f16)(ov * th);
        }
        __syncthreads();                     // writes(w) visible; reads(w^1) done
        x00 = nx00; x01 = nx01; x02 = nx02;
        x10 = nx10; x11 = nx11; x12 = nx12;
    }
    // encoder final: h2(1023) in h2l[0], c2 in regs

    // ---------------- decoder weights (reuse dead encoder registers) -------
    f16x8 D1hh[4][2], W2s[4][2];
    float dxw[4][3], db1[4], db2[4];
#pragma unroll
    for (int g = 0; g < 4; g++) {
        const float s = (g == 2) ? -2.0f : -1.0f;
        const int n = g * 64 + u16;
#pragma unroll
        for (int c = 0; c < 2; c++) {
            const int k0 = c * 32 + quad * 8;
            D1hh[g][c] = ldfrag(d1hh, n, k0, s);
            const float* pa = d2ih + (size_t)n * 64 + k0;
            const float* pb = d2hh + (size_t)n * 64 + k0;
            f16x8 r;
#pragma unroll
            for (int j = 0; j < 8; j++) r[j] = (f16)(s * (pa[j] + pb[j]));
            W2s[g][c] = r;
        }
        dxw[g][0] = s * d1ih[n * 3 + 0];
        dxw[g][1] = s * d1ih[n * 3 + 1];
        dxw[g][2] = s * d1ih[n * 3 + 2];
        db1[g] = s * d1b[n];
        db2[g] = s * d2b[n];
    }
    float fw0 = 0.f, fw1 = 0.f, fw2 = 0.f;
    float fb0 = fcb[0], fb1 = fcb[1], fb2 = fcb[2];
    if (wv < 2) { fw0 = fcW[lane]; fw1 = fcW[64 + lane]; fw2 = fcW[128 + lane]; }

    float cd = c2;
    const float* trow0 = trg + (size_t)(2 * bp) * 1536;
    const float* trow1 = trg + (size_t)(2 * bp + 1) * 1536;
    float t00 = trow0[0], t01 = trow0[1], t02 = trow0[2];
    float t10 = trow1[0], t11 = trow1[1], t12 = trow1[2];

    // ---------------- decoder: 511 steps, 2 barriers each ------------------
#pragma unroll 1
    for (int t = 0; t < 511; t++) {
        const int r = t & 1, w = r ^ 1;
        const int tn = (t + 1 < 511) ? t + 1 : 510;
        float n00 = trow0[tn * 3], n01 = trow0[tn * 3 + 1], n02 = trow0[tn * 3 + 2];
        float n10 = trow1[tn * 3], n11 = trow1[tn * 3 + 1], n12 = trow1[tn * 3 + 2];

        const f16* hp = h2l[r][ab];          // hD(t-1)
        f16x8 a0 = *(const f16x8*)(hp + quad * 8);
        f16x8 a1 = *(const f16x8*)(hp + 32 + quad * 8);

        const float xs0 = qb ? t10 : t00;
        const float xs1 = qb ? t11 : t01;
        const float xs2 = qb ? t12 : t02;

        // dec1
        f32x4 acc[4];
#pragma unroll
        for (int g = 0; g < 4; g++)
            acc[g] = MFMA16(a1, D1hh[g][1], MFMA16(a0, D1hh[g][0], z4));
        float v[4];
#pragma unroll
        for (int g = 0; g < 4; g++) {
            float av = qb ? acc[g][1] : acc[g][0];
            v[g] = av + fmaf(dxw[g][0], xs0,
                        fmaf(dxw[g][1], xs1, fmaf(dxw[g][2], xs2, db1[g])));
        }
        float iv = sig_pre(v[0]), fv = sig_pre(v[1]);
        float gv = 2.0f * sig_pre(v[2]) - 1.0f, ov = sig_pre(v[3]);
        float c1d = fv * cd + iv * gv;
        float th1 = 2.0f * sig_pre(-2.0f * c1d) - 1.0f;
        if (quad < 2) h1l[w][quad][u16] = (f16)(ov * th1);
        __syncthreads();   // B1: h1d visible

        // dec2: x = h = h1d -> summed (Wih2+Whh2)
        const f16* np = h1l[w][ab];
        f16x8 m0 = *(const f16x8*)(np + quad * 8);
        f16x8 m1 = *(const f16x8*)(np + 32 + quad * 8);
#pragma unroll
        for (int g = 0; g < 4; g++)
            acc[g] = MFMA16(m1, W2s[g][1], MFMA16(m0, W2s[g][0], z4));
#pragma unroll
        for (int g = 0; g < 4; g++) {
            float av = qb ? acc[g][1] : acc[g][0];
            v[g] = av + db2[g];
        }
        float i2 = sig_pre(v[0]), f2 = sig_pre(v[1]);
        float g2 = 2.0f * sig_pre(v[2]) - 1.0f, o2 = sig_pre(v[3]);
        float c2d = f2 * c1d + i2 * g2;
        float th2 = 2.0f * sig_pre(-2.0f * c2d) - 1.0f;
        cd = c2d;
        if (quad < 2) h2l[w][quad][u16] = (f16)(o2 * th2);
        __syncthreads();   // B2: hD(t) visible

        if (wv < 2) {      // FC head: wave wv handles batch wv
            float hv = (float)h2l[w][wv][lane];
            float p0 = fw0 * hv, p1 = fw1 * hv, p2 = fw2 * hv;
#pragma unroll
            for (int off = 32; off > 0; off >>= 1) {
                p0 += __shfl_down(p0, off);
                p1 += __shfl_down(p1, off);
                p2 += __shfl_down(p2, off);
            }
            if (lane == 0) {
                float* o = out + ((size_t)(2 * bp + wv) * 512 + t + 1) * 3;
                o[0] = p0 + fb0; o[1] = p1 + fb1; o[2] = p2 + fb2;
            }
        }
        t00 = n00; t01 = n01; t02 = n02;
        t10 = n10; t11 = n11; t12 = n12;
    }
}

extern "C" void kernel_launch(void* const* d_in, const int* in_sizes, int n_in,
                              void* d_out, int out_size, void* d_ws, size_t ws_size,
                              hipStream_t stream)
{
    const float* src   = (const float*)d_in[0];
    const float* trg   = (const float*)d_in[1];
    const float* e1ih  = (const float*)d_in[2];
    const float* e1hh  = (const float*)d_in[3];
    const float* e1b   = (const float*)d_in[4];
    const float* e2ih  = (const float*)d_in[5];
    const float* e2hh  = (const float*)d_in[6];
    const float* e2b   = (const float*)d_in[7];
    const float* dd1ih = (const float*)d_in[8];
    const float* dd1hh = (const float*)d_in[9];
    const float* dd1b  = (const float*)d_in[10];
    const float* dd2ih = (const float*)d_in[11];
    const float* dd2hh = (const float*)d_in[12];
    const float* dd2b  = (const float*)d_in[13];
    const float* fcW   = (const float*)d_in[14];
    const float* fcb   = (const float*)d_in[15];
    float* out = (float*)d_out;

    // outputs[:, 0, :] stays 0; decoder fills t >= 1
    hipMemsetAsync(d_out, 0, (size_t)out_size * sizeof(float), stream);

    seq2seq_kernel<<<256, 256, 0, stream>>>(src, trg,
                                            e1ih, e1hh, e1b, e2ih, e2hh, e2b,
                                            dd1ih, dd1hh, dd1b, dd2ih, dd2hh, dd2b,
                                            fcW, fcb, out);
}